// Round 2
// baseline (414.116 us; speedup 1.0000x reference)
//
#include <hip/hip_runtime.h>
#include <hip/hip_bf16.h>
#include <hip/hip_fp8.h>
#include <math.h>

#define UCNT 50000
#define ICNT 25000
#define NNODE 75000
#define DDIM 64
#define BB 4096
#define EPS_C 0.2f
#define INV_TEMP 5.0f
#define NJT (BB / 64)       // 64 j-tiles in infonce

#define NRANGE 293          // 256-node ranges
#define RB_U 196            // user-half ranges (0..195; range 195 shared w/ items)
#define RB_I 98             // item-half ranges (195..292 -> rel 0..97)
#define GOFF_I 195
#define EPB 4096            // edges per partition block (both halves)
#define YS 64.0f            // fp8 y scale (keeps elements in e4m3 normal range)
#define YSI (1.0f / 64.0f)

typedef float floatx4 __attribute__((ext_vector_type(4)));
typedef float floatx2 __attribute__((ext_vector_type(2)));
typedef unsigned short ushortx4 __attribute__((ext_vector_type(4)));
typedef short shortx8 __attribute__((ext_vector_type(8)));

__device__ __forceinline__ float wave_sum(float x) {
#pragma unroll
  for (int m = 32; m >= 1; m >>= 1) x += __shfl_xor(x, m, 64);
  return x;
}

__device__ __forceinline__ unsigned short f2bf(float f) {   // RNE
  unsigned u = __float_as_uint(f);
  u += 0x7fffu + ((u >> 16) & 1u);
  return (unsigned short)(u >> 16);
}
// HW fp8 (OCP e4m3 on gfx950) encode pair / decode single
__device__ __forceinline__ unsigned enc_pk4(float a, float b, float c, float d) {
  int w = 0;
  w = __builtin_amdgcn_cvt_pk_fp8_f32(a, b, w, false);   // bytes 0,1
  w = __builtin_amdgcn_cvt_pk_fp8_f32(c, d, w, true);    // bytes 2,3
  return (unsigned)w;
}
__device__ __forceinline__ float fp8dec1(unsigned char b) {
  return __builtin_amdgcn_cvt_f32_fp8((int)b, 0);
}

// ---------------- pcount: per (stripe-block, range) histogram -> bcnt column ---------
__global__ __launch_bounds__(256) void pcount_kernel(const int* __restrict__ src,
                                                     int* __restrict__ bcnt,
                                                     int ne, int nbu, int nbp) {
  __shared__ int qc[RB_U];
  int t = threadIdx.x;
  int b = blockIdx.x;
  int eh = ne >> 1;
  bool isU = b < nbu;
  int base = isU ? b * EPB : eh + (b - nbu) * EPB;
  int lim = min(base + EPB, isU ? eh : ne);
  int RB = isU ? RB_U : RB_I;
  int goff = isU ? 0 : GOFF_I;
  for (int i = t; i < RB; i += 256) qc[i] = 0;
  __syncthreads();
  for (int i = base + t; i < lim; i += 256) {
    int s = __builtin_nontemporal_load(src + i);
    atomicAdd(&qc[(s >> 8) - goff], 1);
  }
  __syncthreads();
  for (int r = t; r < NRANGE; r += 256) {
    int rel = r - goff;
    int v = (rel >= 0 && rel < RB) ? qc[rel] : 0;
    bcnt[(size_t)r * nbp + b] = v;
  }
}

// ---------------- pscan: per range, local exclusive scan over block columns ----------
__global__ __launch_bounds__(256) void pscan_kernel(const int* __restrict__ bcnt,
                                                    int* __restrict__ boff,
                                                    int* __restrict__ rtot, int nbp) {
  __shared__ int s0[512], s1[512];
  int r = blockIdx.x, t = threadIdx.x;
  for (int j = t; j < 512; j += 256) s0[j] = (j < nbp) ? bcnt[(size_t)r * nbp + j] : 0;
  __syncthreads();
  int* a = s0;
  int* bf = s1;
  for (int off = 1; off < 512; off <<= 1) {
    for (int j = t; j < 512; j += 256) bf[j] = a[j] + ((j >= off) ? a[j - off] : 0);
    __syncthreads();
    int* tmp = a; a = bf; bf = tmp;
  }
  for (int j = t; j < nbp; j += 256)
    boff[(size_t)r * nbp + j] = a[j] - bcnt[(size_t)r * nbp + j];
  if (t == 0) rtot[r] = a[511];
}

// ---------------- cscan2: scan 293 range totals -> cbase ----------------
__global__ __launch_bounds__(512) void cscan2_kernel(const int* __restrict__ rtot,
                                                     int* __restrict__ cbase,
                                                     int* __restrict__ row_ptr, int ne) {
  int t = threadIdx.x;
  int lane = t & 63, wid = t >> 6;
  int c = (t < NRANGE) ? rtot[t] : 0;
  int v = c;
#pragma unroll
  for (int d = 1; d < 64; d <<= 1) {
    int u = __shfl_up(v, d, 64);
    if (lane >= d) v += u;
  }
  __shared__ int ws[8], wo[8];
  if (lane == 63) ws[wid] = v;
  __syncthreads();
  if (t == 0) {
    int run = 0;
    for (int k = 0; k < 8; ++k) { wo[k] = run; run += ws[k]; }
    row_ptr[NNODE] = ne;
  }
  __syncthreads();
  if (t < NRANGE) cbase[t] = v - c + wo[wid];
}

// ---------------- pscatter: deterministic binning into u32 (srcLow8 | dst) -----------
__global__ __launch_bounds__(256) void pscatter_kernel(const int* __restrict__ src,
                                                       const int* __restrict__ dst,
                                                       const int* __restrict__ boff,
                                                       const int* __restrict__ cbase,
                                                       unsigned* __restrict__ binned,
                                                       int ne, int nbu, int nbp) {
  __shared__ int qc[RB_U];
  int t = threadIdx.x;
  int b = blockIdx.x;
  int eh = ne >> 1;
  bool isU = b < nbu;
  int base = isU ? b * EPB : eh + (b - nbu) * EPB;
  int lim = min(base + EPB, isU ? eh : ne);
  int goff = isU ? 0 : GOFF_I;
  int RB = isU ? RB_U : RB_I;
  for (int i = t; i < RB; i += 256) qc[i] = 0;
  __syncthreads();
  for (int i = base + t; i < lim; i += 256) {
    int s = __builtin_nontemporal_load(src + i);
    int d = __builtin_nontemporal_load(dst + i);
    int rb = (s >> 8) - goff;
    int pos = atomicAdd(&qc[rb], 1);
    int rg = rb + goff;
    int g = cbase[rg] + boff[(size_t)rg * nbp + b] + pos;
    binned[g] = ((unsigned)(s & 255) << 24) | (unsigned)d;   // dst < 2^24
  }
}

// ---------------- place: one block per range -> row_ptr, counts, csr (private region)
__global__ __launch_bounds__(256) void place_kernel(
    const unsigned* __restrict__ binned, const int* __restrict__ cbase,
    int* __restrict__ row_ptr, int* __restrict__ counts,
    int* __restrict__ csr_dst, int ne) {
  __shared__ int cnt[256], cur[256], ws[4], wo[4];
  int t = threadIdx.x;
  int b = blockIdx.x;
  int r0 = b << 8;
  int seg0 = cbase[b];
  int seg1 = (b == NRANGE - 1) ? ne : cbase[b + 1];
  cnt[t] = 0;
  __syncthreads();
  for (int j = seg0 + t; j < seg1; j += 256)
    atomicAdd(&cnt[binned[j] >> 24], 1);
  __syncthreads();
  int c = cnt[t];
  int lane = t & 63, wid = t >> 6;
  int v = c;
#pragma unroll
  for (int d = 1; d < 64; d <<= 1) {
    int u = __shfl_up(v, d, 64);
    if (lane >= d) v += u;
  }
  if (lane == 63) ws[wid] = v;
  __syncthreads();
  if (t == 0) {
    int run = 0;
    for (int k = 0; k < 4; ++k) { wo[k] = run; run += ws[k]; }
  }
  __syncthreads();
  int excl = v - c + wo[wid];
  if (r0 + t < NNODE) {
    row_ptr[r0 + t] = seg0 + excl;
    counts[r0 + t] = c;
  }
  cur[t] = excl;
  __syncthreads();
  for (int j = seg0 + t; j < seg1; j += 256) {
    unsigned e = binned[j];
    int off = atomicAdd(&cur[e >> 24], 1);
    csr_dst[seg0 + off] = (int)(e & 0xFFFFFFu);
  }
}

// ---------------- prescale: y_init[n] = fp8(table[n] * rsqrt(max(deg,1)) * YS) -------
// also initializes the dummy zero row at index NNODE (used for padded gathers)
__global__ __launch_bounds__(256) void prescale_kernel(const float* __restrict__ ut,
                                                       const float* __restrict__ it,
                                                       const int* __restrict__ counts,
                                                       unsigned char* __restrict__ y) {
  int idx = blockIdx.x * 256 + threadIdx.x;   // one 4-dim group per thread
  if (idx >= (NNODE + 1) * 16) return;
  int n = idx >> 4;
  if (n == NNODE) {                           // dummy zero row
    *(unsigned*)(y + (size_t)idx * 4) = 0u;
    return;
  }
  float sc = rsqrtf(fmaxf((float)counts[n], 1.f)) * YS;
  const float* srcp = (n < UCNT) ? (ut + (size_t)n * DDIM)
                                 : (it + (size_t)(n - UCNT) * DDIM);
  float4 v = *(const float4*)(srcp + (idx & 15) * 4);
  *(unsigned*)(y + (size_t)idx * 4) = enc_pk4(v.x * sc, v.y * sc, v.z * sc, v.w * sc);
}

// ---------------- SpMM, lane = dim: scalar edge indices, zero cross-lane reduction ---
// One wave per row. 64 lanes = 64 dims. Edge indices are wave-uniform -> v_readlane
// into SGPR; every gather is global_load_ubyte with SGPR base + lane offset (one 64B
// line per edge, fully coalesced, no per-lane address math). Out-of-range slots in the
// 8-wide unrolled body clamp (scalar select) to the dummy zero row NNODE.
__global__ __launch_bounds__(256) void spmm_kernel(const unsigned char* __restrict__ y_in,
                                                   const int* __restrict__ row_ptr,
                                                   const int* __restrict__ csr_dst,
                                                   const int* __restrict__ counts,
                                                   const float* __restrict__ noise,
                                                   unsigned char* __restrict__ y_out) {
  int wave = blockIdx.x * 4 + (threadIdx.x >> 6);
  int lane = threadIdx.x & 63;
  if (wave > NNODE) return;
  int r = wave;
  if (r == NNODE) {                   // keep dummy zero row alive in the output buffer
    y_out[(size_t)NNODE * DDIM + lane] = 0;
    return;
  }
  int beg = __builtin_amdgcn_readfirstlane(row_ptr[r]);
  int endp = __builtin_amdgcn_readfirstlane(row_ptr[r + 1]);
  // issue lane-local epilogue inputs early (hide under the gather)
  float nf = __builtin_nontemporal_load(noise + (size_t)r * DDIM + lane);
  float scr = rsqrtf(fmaxf((float)counts[r], 1.f));

  float acc0 = 0.f, acc1 = 0.f;
  for (int e0 = beg; e0 < endp; e0 += 64) {          // chunk loop (scalar bounds)
    int cnt = min(endp - e0, 64);                    // wave-uniform
    int d = __builtin_nontemporal_load(csr_dst + e0 + lane);  // csr padded by 64 ints
    for (int j = 0; j < cnt; j += 8) {               // uniform inner loop
      unsigned char bv[8];
#pragma unroll
      for (int k = 0; k < 8; ++k) {
        int ik = (j + k < cnt) ? __builtin_amdgcn_readlane(d, j + k) : NNODE;
        bv[k] = y_in[(size_t)ik * DDIM + lane];      // saddr + lane, 64B line
      }
#pragma unroll
      for (int k = 0; k < 8; k += 2) {
        acc0 += __builtin_amdgcn_cvt_f32_fp8((int)bv[k], 0);
        acc1 += __builtin_amdgcn_cvt_f32_fp8((int)bv[k + 1], 0);
      }
    }
  }
  float acc = acc0 + acc1;

  float ss = wave_sum(nf * nf);                      // full 64-dim noise norm
  float inv = EPS_C / fmaxf(sqrtf(ss), 1e-12f);
  float x = acc * scr * YSI;                         // undo fp8 scale from gathered terms
  float sgn = (x > 0.f) ? 1.f : ((x < 0.f) ? -1.f : 0.f);
  float o = (x + sgn * nf * inv) * scr * YS;         // store y = x_out * sc (scaled)
  unsigned pk = enc_pk4(o, o, o, o);
  y_out[(size_t)r * DDIM + lane] = (unsigned char)(pk & 0xffu);
}

// ---------------- batch gather: BPR, reg, bf16 normalized InfoNCE inputs -------------
__global__ __launch_bounds__(256) void batch_kernel(
    const unsigned char* __restrict__ yb0, const unsigned char* __restrict__ yb1,
    const unsigned char* __restrict__ yb2,
    const float* __restrict__ ut, const float* __restrict__ it,
    const int* __restrict__ counts,
    const int* __restrict__ user, const int* __restrict__ pos, const int* __restrict__ neg,
    unsigned short* __restrict__ z1u, unsigned short* __restrict__ z2u,
    unsigned short* __restrict__ z1i, unsigned short* __restrict__ z2i,
    float* __restrict__ pos_u, float* __restrict__ pos_i,
    float* __restrict__ sp_arr, float* __restrict__ rr_arr) {
  int wave = blockIdx.x * (blockDim.x >> 6) + (threadIdx.x >> 6);
  int lane = threadIdx.x & 63;
  if (wave >= BB) return;
  int b = wave;
  int iu = user[b], ip = pos[b], ing = neg[b];
  float s_u = sqrtf(fmaxf((float)counts[iu], 1.f)) * YSI;
  float s_p = sqrtf(fmaxf((float)counts[UCNT + ip], 1.f)) * YSI;
  float s_n = sqrtf(fmaxf((float)counts[UCNT + ing], 1.f)) * YSI;
  size_t ru = (size_t)iu * DDIM + lane;
  size_t rp = (size_t)(UCNT + ip) * DDIM + lane;
  size_t rn = (size_t)(UCNT + ing) * DDIM + lane;
  float cu = fp8dec1(yb0[ru]) * s_u;        // x_cl user row
  float ci = fp8dec1(yb0[rp]) * s_p;        // x_cl positive-item row
  float ue = (cu + (fp8dec1(yb1[ru]) + fp8dec1(yb2[ru])) * s_u) * (1.f / 3.f);
  float pe = (ci + (fp8dec1(yb1[rp]) + fp8dec1(yb2[rp])) * s_p) * (1.f / 3.f);
  float ne = (fp8dec1(yb0[rn]) + fp8dec1(yb1[rn]) + fp8dec1(yb2[rn])) * s_n * (1.f / 3.f);

  float ps = wave_sum(ue * pe);
  float ns = wave_sum(ue * ne);
  float x = ns - ps;
  float sp = fmaxf(x, 0.f) + log1pf(expf(-fabsf(x)));

  float eu = ut[(size_t)iu * DDIM + lane];
  float ep = it[(size_t)ip * DDIM + lane];
  float en = it[(size_t)ing * DDIM + lane];
  float rr = wave_sum(eu * eu + ep * ep + en * en);
  if (lane == 0) { sp_arr[b] = sp; rr_arr[b] = rr; }

  float n1 = fmaxf(sqrtf(wave_sum(cu * cu)), 1e-12f);
  float n2 = fmaxf(sqrtf(wave_sum(ue * ue)), 1e-12f);
  float d12 = wave_sum(cu * ue);
  z1u[(size_t)b * DDIM + lane] = f2bf(cu / n1);
  z2u[(size_t)b * DDIM + lane] = f2bf(ue / n2);
  if (lane == 0) pos_u[b] = d12 / (n1 * n2) * INV_TEMP;

  float m1 = fmaxf(sqrtf(wave_sum(ci * ci)), 1e-12f);
  float m2 = fmaxf(sqrtf(wave_sum(pe * pe)), 1e-12f);
  float e12 = wave_sum(ci * pe);
  z1i[(size_t)b * DDIM + lane] = f2bf(ci / m1);
  z2i[(size_t)b * DDIM + lane] = f2bf(pe / m2);
  if (lane == 0) pos_i[b] = e12 / (m1 * m2) * INV_TEMP;
}

// ---------------- InfoNCE via MFMA: one wave = 16x16 tile, K=64 ----------------------
__global__ __launch_bounds__(256) void infonce_kernel(const unsigned short* __restrict__ Z1,
                                                      const unsigned short* __restrict__ Z2,
                                                      float* __restrict__ rowpart) {
  __shared__ float part[16];
  int t = threadIdx.x;
  if (t < 16) part[t] = 0.f;
  __syncthreads();
  int wv = t >> 6, lane = t & 63;
  int i0 = blockIdx.y * 16;              // 16-row i-tile (shared by 4 waves)
  int j0 = blockIdx.x * 64 + wv * 16;    // each wave: its own 16-col group
  int m = lane & 15, q = lane >> 4;
  const unsigned short* ap = Z1 + (size_t)(i0 + m) * DDIM + q * 8;
  const unsigned short* bp = Z2 + (size_t)(j0 + m) * DDIM + q * 8;
  shortx8 a0 = *(const shortx8*)ap;
  shortx8 a1 = *(const shortx8*)(ap + 32);
  shortx8 b0 = *(const shortx8*)bp;
  shortx8 b1 = *(const shortx8*)(bp + 32);
  floatx4 acc = {0.f, 0.f, 0.f, 0.f};
  acc = __builtin_amdgcn_mfma_f32_16x16x32_bf16(a0, b0, acc, 0, 0, 0);
  acc = __builtin_amdgcn_mfma_f32_16x16x32_bf16(a1, b1, acc, 0, 0, 0);
  float s[4];
#pragma unroll
  for (int r = 0; r < 4; ++r) s[r] = __expf(acc[r] * INV_TEMP);
#pragma unroll
  for (int mm = 1; mm <= 8; mm <<= 1)
#pragma unroll
    for (int r = 0; r < 4; ++r) s[r] += __shfl_xor(s[r], mm, 64);
  if (m == 0) {
#pragma unroll
    for (int r = 0; r < 4; ++r) atomicAdd(&part[q * 4 + r], s[r]);
  }
  __syncthreads();
  if (t < 16) rowpart[(size_t)blockIdx.x * BB + i0 + t] = part[t];
}

// ---------------- reduce 64 partials per row into rowsum ----------------
__global__ __launch_bounds__(256) void reduce_kernel(const float* __restrict__ rowpart_u,
                                                     const float* __restrict__ rowpart_i,
                                                     float* __restrict__ rowsum_u,
                                                     float* __restrict__ rowsum_i) {
  int i = blockIdx.x * 256 + threadIdx.x;   // row index
  const float* src = blockIdx.y ? rowpart_i : rowpart_u;
  float s = 0.f;
#pragma unroll 8
  for (int jb = 0; jb < NJT; ++jb) s += __builtin_nontemporal_load(src + (size_t)jb * BB + i);
  if (blockIdx.y) rowsum_i[i] = s; else rowsum_u[i] = s;
}

// ---------------- finalize ----------------
__global__ __launch_bounds__(256) void finalize_kernel(const float* __restrict__ rowsum_u,
                                                       const float* __restrict__ pos_u,
                                                       const float* __restrict__ rowsum_i,
                                                       const float* __restrict__ pos_i,
                                                       const float* __restrict__ sp_arr,
                                                       const float* __restrict__ rr_arr,
                                                       float* __restrict__ out) {
  int t = threadIdx.x;
  float su = 0.f, si = 0.f, sb = 0.f, sr = 0.f;
  for (int i = t; i < BB; i += 256) {
    su += logf(rowsum_u[i]) - pos_u[i];
    si += logf(rowsum_i[i]) - pos_i[i];
    sb += sp_arr[i];
    sr += rr_arr[i];
  }
  su = wave_sum(su);
  si = wave_sum(si);
  sb = wave_sum(sb);
  sr = wave_sum(sr);
  __shared__ float sh[16];
  int lane = t & 63, wid = t >> 6;
  if (lane == 0) { sh[wid] = su; sh[4 + wid] = si; sh[8 + wid] = sb; sh[12 + wid] = sr; }
  __syncthreads();
  if (t == 0) {
    float SU = sh[0] + sh[1] + sh[2] + sh[3];
    float SI = sh[4] + sh[5] + sh[6] + sh[7];
    float SB = sh[8] + sh[9] + sh[10] + sh[11];
    float SR = sh[12] + sh[13] + sh[14] + sh[15];
    out[0] = SB * (1.f / BB);
    out[1] = 1e-4f * 0.5f * SR * (1.f / BB);
    out[2] = 0.2f * ((SU + SI) * (1.f / BB));
  }
}

extern "C" void kernel_launch(void* const* d_in, const int* in_sizes, int n_in,
                              void* d_out, int out_size, void* d_ws, size_t ws_size,
                              hipStream_t stream) {
  const float* user_table = (const float*)d_in[0];
  const float* item_table = (const float*)d_in[1];
  const float* noise      = (const float*)d_in[3];
  const int*   edge_src   = (const int*)d_in[4];
  const int*   edge_dst   = (const int*)d_in[5];
  const int*   user       = (const int*)d_in[6];
  const int*   positive   = (const int*)d_in[7];
  const int*   negative   = (const int*)d_in[8];
  const int E2 = in_sizes[2];  // 2,000,000

  const int eh = E2 >> 1;
  const int nbu = (eh + EPB - 1) / EPB;            // 245
  const int nbi = (E2 - eh + EPB - 1) / EPB;       // 245
  const int nbp = nbu + nbi;                       // 490

  char* w = (char*)d_ws;
  auto alloc = [&](size_t bytes) -> void* {
    void* p = (void*)w;
    w += (bytes + 255) & ~(size_t)255;
    return p;
  };
  int*   cbase    = (int*)alloc((size_t)NRANGE * 4);
  int*   rtot     = (int*)alloc((size_t)NRANGE * 4);
  int*   bcnt     = (int*)alloc((size_t)NRANGE * nbp * 4);
  int*   boff     = (int*)alloc((size_t)NRANGE * nbp * 4);
  int*   row_ptr  = (int*)alloc((size_t)(NNODE + 1) * 4);
  int*   counts   = (int*)alloc((size_t)NNODE * 4);
  int*   csr_dst  = (int*)alloc((size_t)(E2 + 64) * 4);   // +64 pad: unpredicated chunk load
  unsigned* binned = (unsigned*)alloc((size_t)E2 * 4);
  unsigned char* y_init = (unsigned char*)alloc((size_t)(NNODE + 1) * DDIM);
  unsigned char* yb0    = (unsigned char*)alloc((size_t)(NNODE + 1) * DDIM);
  unsigned char* yb1    = (unsigned char*)alloc((size_t)(NNODE + 1) * DDIM);
  unsigned char* yb2    = (unsigned char*)alloc((size_t)(NNODE + 1) * DDIM);
  unsigned short* z1u    = (unsigned short*)alloc((size_t)BB * DDIM * 2);
  unsigned short* z2u    = (unsigned short*)alloc((size_t)BB * DDIM * 2);
  unsigned short* z1i    = (unsigned short*)alloc((size_t)BB * DDIM * 2);
  unsigned short* z2i    = (unsigned short*)alloc((size_t)BB * DDIM * 2);
  float* pos_u    = (float*)alloc((size_t)BB * 4);
  float* pos_i    = (float*)alloc((size_t)BB * 4);
  float* rowsum_u = (float*)alloc((size_t)BB * 4);
  float* rowsum_i = (float*)alloc((size_t)BB * 4);
  float* sp_arr   = (float*)alloc((size_t)BB * 4);
  float* rr_arr   = (float*)alloc((size_t)BB * 4);
  float* rowpart_u = (float*)alloc((size_t)NJT * BB * 4);
  float* rowpart_i = (float*)alloc((size_t)NJT * BB * 4);

  pcount_kernel<<<nbp, 256, 0, stream>>>(edge_src, bcnt, E2, nbu, nbp);
  pscan_kernel<<<NRANGE, 256, 0, stream>>>(bcnt, boff, rtot, nbp);
  cscan2_kernel<<<1, 512, 0, stream>>>(rtot, cbase, row_ptr, E2);
  pscatter_kernel<<<nbp, 256, 0, stream>>>(edge_src, edge_dst, boff, cbase, binned,
                                           E2, nbu, nbp);
  place_kernel<<<NRANGE, 256, 0, stream>>>(binned, cbase, row_ptr, counts, csr_dst, E2);
  prescale_kernel<<<((NNODE + 1) * 16 + 255) / 256, 256, 0, stream>>>(user_table, item_table,
                                                                      counts, y_init);
  const int spmm_blocks = (NNODE + 1 + 3) / 4;  // 4 waves per 256-thread block (+dummy row)
  spmm_kernel<<<spmm_blocks, 256, 0, stream>>>(y_init, row_ptr, csr_dst, counts,
                                               noise + (size_t)0 * NNODE * DDIM, yb0);
  spmm_kernel<<<spmm_blocks, 256, 0, stream>>>(yb0, row_ptr, csr_dst, counts,
                                               noise + (size_t)1 * NNODE * DDIM, yb1);
  spmm_kernel<<<spmm_blocks, 256, 0, stream>>>(yb1, row_ptr, csr_dst, counts,
                                               noise + (size_t)2 * NNODE * DDIM, yb2);
  batch_kernel<<<BB / 4, 256, 0, stream>>>(yb0, yb1, yb2, user_table, item_table, counts,
                                           user, positive, negative,
                                           z1u, z2u, z1i, z2i, pos_u, pos_i, sp_arr, rr_arr);
  dim3 ig(NJT, BB / 16);
  infonce_kernel<<<ig, 256, 0, stream>>>(z1u, z2u, rowpart_u);
  infonce_kernel<<<ig, 256, 0, stream>>>(z1i, z2i, rowpart_i);
  dim3 rg(BB / 256, 2);
  reduce_kernel<<<rg, 256, 0, stream>>>(rowpart_u, rowpart_i, rowsum_u, rowsum_i);
  finalize_kernel<<<1, 256, 0, stream>>>(rowsum_u, pos_u, rowsum_i, pos_i,
                                         sp_arr, rr_arr, (float*)d_out);
}

// Round 3
// 363.775 us; speedup vs baseline: 1.1384x; 1.1384x over previous
//
#include <hip/hip_runtime.h>
#include <hip/hip_bf16.h>
#include <hip/hip_fp8.h>
#include <math.h>

#define UCNT 50000
#define ICNT 25000
#define NNODE 75000
#define DDIM 64
#define BB 4096
#define EPS_C 0.2f
#define INV_TEMP 5.0f
#define NJT (BB / 64)       // 64 j-tiles in infonce

#define NRANGE 293          // 256-node ranges
#define RB_U 196            // user-half ranges (0..195; range 195 shared w/ items)
#define RB_I 98             // item-half ranges (195..292 -> rel 0..97)
#define GOFF_I 195
#define EPB 4096            // edges per partition block (both halves)
#define YS 64.0f            // fp8 y scale (keeps elements in e4m3 normal range)
#define YSI (1.0f / 64.0f)

typedef float floatx4 __attribute__((ext_vector_type(4)));
typedef float floatx2 __attribute__((ext_vector_type(2)));
typedef unsigned short ushortx4 __attribute__((ext_vector_type(4)));
typedef short shortx8 __attribute__((ext_vector_type(8)));

__device__ __forceinline__ float wave_sum(float x) {
#pragma unroll
  for (int m = 32; m >= 1; m >>= 1) x += __shfl_xor(x, m, 64);
  return x;
}

__device__ __forceinline__ unsigned short f2bf(float f) {   // RNE
  unsigned u = __float_as_uint(f);
  u += 0x7fffu + ((u >> 16) & 1u);
  return (unsigned short)(u >> 16);
}
// HW fp8 (OCP e4m3 on gfx950) encode pair / decode single
__device__ __forceinline__ unsigned enc_pk4(float a, float b, float c, float d) {
  int w = 0;
  w = __builtin_amdgcn_cvt_pk_fp8_f32(a, b, w, false);   // bytes 0,1
  w = __builtin_amdgcn_cvt_pk_fp8_f32(c, d, w, true);    // bytes 2,3
  return (unsigned)w;
}
__device__ __forceinline__ float fp8dec1(unsigned char b) {
  return __builtin_amdgcn_cvt_f32_fp8((int)b, 0);
}

// ---------------- pcount: per (stripe-block, range) histogram -> bcnt column ---------
__global__ __launch_bounds__(256) void pcount_kernel(const int* __restrict__ src,
                                                     int* __restrict__ bcnt,
                                                     int ne, int nbu, int nbp) {
  __shared__ int qc[RB_U];
  int t = threadIdx.x;
  int b = blockIdx.x;
  int eh = ne >> 1;
  bool isU = b < nbu;
  int base = isU ? b * EPB : eh + (b - nbu) * EPB;
  int lim = min(base + EPB, isU ? eh : ne);
  int RB = isU ? RB_U : RB_I;
  int goff = isU ? 0 : GOFF_I;
  for (int i = t; i < RB; i += 256) qc[i] = 0;
  __syncthreads();
  for (int i = base + t; i < lim; i += 256) {
    int s = __builtin_nontemporal_load(src + i);
    atomicAdd(&qc[(s >> 8) - goff], 1);
  }
  __syncthreads();
  for (int r = t; r < NRANGE; r += 256) {
    int rel = r - goff;
    int v = (rel >= 0 && rel < RB) ? qc[rel] : 0;
    bcnt[(size_t)r * nbp + b] = v;
  }
}

// ---------------- pscan: per range, local exclusive scan over block columns ----------
__global__ __launch_bounds__(256) void pscan_kernel(const int* __restrict__ bcnt,
                                                    int* __restrict__ boff,
                                                    int* __restrict__ rtot, int nbp) {
  __shared__ int s0[512], s1[512];
  int r = blockIdx.x, t = threadIdx.x;
  for (int j = t; j < 512; j += 256) s0[j] = (j < nbp) ? bcnt[(size_t)r * nbp + j] : 0;
  __syncthreads();
  int* a = s0;
  int* bf = s1;
  for (int off = 1; off < 512; off <<= 1) {
    for (int j = t; j < 512; j += 256) bf[j] = a[j] + ((j >= off) ? a[j - off] : 0);
    __syncthreads();
    int* tmp = a; a = bf; bf = tmp;
  }
  for (int j = t; j < nbp; j += 256)
    boff[(size_t)r * nbp + j] = a[j] - bcnt[(size_t)r * nbp + j];
  if (t == 0) rtot[r] = a[511];
}

// ---------------- cscan2: scan 293 range totals -> cbase ----------------
__global__ __launch_bounds__(512) void cscan2_kernel(const int* __restrict__ rtot,
                                                     int* __restrict__ cbase,
                                                     int* __restrict__ row_ptr, int ne) {
  int t = threadIdx.x;
  int lane = t & 63, wid = t >> 6;
  int c = (t < NRANGE) ? rtot[t] : 0;
  int v = c;
#pragma unroll
  for (int d = 1; d < 64; d <<= 1) {
    int u = __shfl_up(v, d, 64);
    if (lane >= d) v += u;
  }
  __shared__ int ws[8], wo[8];
  if (lane == 63) ws[wid] = v;
  __syncthreads();
  if (t == 0) {
    int run = 0;
    for (int k = 0; k < 8; ++k) { wo[k] = run; run += ws[k]; }
    row_ptr[NNODE] = ne;
  }
  __syncthreads();
  if (t < NRANGE) cbase[t] = v - c + wo[wid];
}

// ---------------- pscatter: deterministic binning into u32 (srcLow8 | dst) -----------
__global__ __launch_bounds__(256) void pscatter_kernel(const int* __restrict__ src,
                                                       const int* __restrict__ dst,
                                                       const int* __restrict__ boff,
                                                       const int* __restrict__ cbase,
                                                       unsigned* __restrict__ binned,
                                                       int ne, int nbu, int nbp) {
  __shared__ int qc[RB_U];
  int t = threadIdx.x;
  int b = blockIdx.x;
  int eh = ne >> 1;
  bool isU = b < nbu;
  int base = isU ? b * EPB : eh + (b - nbu) * EPB;
  int lim = min(base + EPB, isU ? eh : ne);
  int goff = isU ? 0 : GOFF_I;
  int RB = isU ? RB_U : RB_I;
  for (int i = t; i < RB; i += 256) qc[i] = 0;
  __syncthreads();
  for (int i = base + t; i < lim; i += 256) {
    int s = __builtin_nontemporal_load(src + i);
    int d = __builtin_nontemporal_load(dst + i);
    int rb = (s >> 8) - goff;
    int pos = atomicAdd(&qc[rb], 1);
    int rg = rb + goff;
    int g = cbase[rg] + boff[(size_t)rg * nbp + b] + pos;
    binned[g] = ((unsigned)(s & 255) << 24) | (unsigned)d;   // dst < 2^24
  }
}

// ---------------- place: one block per range -> row_ptr, counts, csr (private region)
__global__ __launch_bounds__(256) void place_kernel(
    const unsigned* __restrict__ binned, const int* __restrict__ cbase,
    int* __restrict__ row_ptr, int* __restrict__ counts,
    int* __restrict__ csr_dst, int ne) {
  __shared__ int cnt[256], cur[256], ws[4], wo[4];
  int t = threadIdx.x;
  int b = blockIdx.x;
  int r0 = b << 8;
  int seg0 = cbase[b];
  int seg1 = (b == NRANGE - 1) ? ne : cbase[b + 1];
  cnt[t] = 0;
  __syncthreads();
  for (int j = seg0 + t; j < seg1; j += 256)
    atomicAdd(&cnt[binned[j] >> 24], 1);
  __syncthreads();
  int c = cnt[t];
  int lane = t & 63, wid = t >> 6;
  int v = c;
#pragma unroll
  for (int d = 1; d < 64; d <<= 1) {
    int u = __shfl_up(v, d, 64);
    if (lane >= d) v += u;
  }
  if (lane == 63) ws[wid] = v;
  __syncthreads();
  if (t == 0) {
    int run = 0;
    for (int k = 0; k < 4; ++k) { wo[k] = run; run += ws[k]; }
  }
  __syncthreads();
  int excl = v - c + wo[wid];
  if (r0 + t < NNODE) {
    row_ptr[r0 + t] = seg0 + excl;
    counts[r0 + t] = c;
  }
  cur[t] = excl;
  __syncthreads();
  for (int j = seg0 + t; j < seg1; j += 256) {
    unsigned e = binned[j];
    int off = atomicAdd(&cur[e >> 24], 1);
    csr_dst[seg0 + off] = (int)(e & 0xFFFFFFu);
  }
}

// ---------------- prescale: y_init[n] = fp8(table[n] * rsqrt(max(deg,1)) * YS) -------
// also initializes the dummy zero row at index NNODE (used for padded gathers)
__global__ __launch_bounds__(256) void prescale_kernel(const float* __restrict__ ut,
                                                       const float* __restrict__ it,
                                                       const int* __restrict__ counts,
                                                       unsigned char* __restrict__ y) {
  int idx = blockIdx.x * 256 + threadIdx.x;   // one 4-dim group per thread
  if (idx >= (NNODE + 1) * 16) return;
  int n = idx >> 4;
  if (n == NNODE) {                           // dummy zero row
    *(unsigned*)(y + (size_t)idx * 4) = 0u;
    return;
  }
  float sc = rsqrtf(fmaxf((float)counts[n], 1.f)) * YS;
  const float* srcp = (n < UCNT) ? (ut + (size_t)n * DDIM)
                                 : (it + (size_t)(n - UCNT) * DDIM);
  float4 v = *(const float4*)(srcp + (idx & 15) * 4);
  *(unsigned*)(y + (size_t)idx * 4) = enc_pk4(v.x * sc, v.y * sc, v.z * sc, v.w * sc);
}

// ---- gather helpers: 8 edge-groups x 8 dim-slices; issue all, then consume ----------
__device__ __forceinline__ void gather_issue(const unsigned char* __restrict__ yb,
                                             int d, int nit, int g, unsigned voff,
                                             uint2* pk) {
#pragma unroll
  for (int j = 0; j < 8; ++j) {
    if (j < nit) {
      int dj = __shfl(d, j * 8 + g, 64);
      pk[j] = *(const uint2*)(yb + (((unsigned)dj << 6) + voff));   // 32-bit voffset
    }
  }
}
__device__ __forceinline__ void gather_acc(const uint2* pk, int nit,
                                           floatx2& a0, floatx2& a1,
                                           floatx2& a2, floatx2& a3) {
#pragma unroll
  for (int j = 0; j < 8; ++j) {
    if (j < nit) {
      a0 += __builtin_amdgcn_cvt_pk_f32_fp8(pk[j].x, 0);
      a1 += __builtin_amdgcn_cvt_pk_f32_fp8(pk[j].x, 1);
      a2 += __builtin_amdgcn_cvt_pk_f32_fp8(pk[j].y, 0);
      a3 += __builtin_amdgcn_cvt_pk_f32_fp8(pk[j].y, 1);
    }
  }
}

// ---------------- SpMM: 2 adjacent rows per wave, all gathers in flight --------------
// R1 group-gather structure (8 edges per VMEM instr) + dual independent row chains:
// csr loads + up to 16 row-gathers issue back-to-back before any consume. row_ptr /
// counts are read via readfirstlane(wave)-derived indices -> provably uniform -> s_load.
__global__ __launch_bounds__(256) void spmm_kernel(const unsigned char* __restrict__ y_in,
                                                   const int* __restrict__ row_ptr,
                                                   const int* __restrict__ csr_dst,
                                                   const int* __restrict__ counts,
                                                   const float* __restrict__ noise,
                                                   unsigned char* __restrict__ y_out) {
  int wv = __builtin_amdgcn_readfirstlane(blockIdx.x * 4 + (threadIdx.x >> 6));
  int lane = threadIdx.x & 63;
  if (wv > NNODE / 2) return;
  int g = lane >> 3, l8 = lane & 7;
  unsigned voff = (unsigned)(l8 * 8);
  if (wv == NNODE / 2) {              // keep dummy zero row alive in the output buffer
    if (g == 0) {
      uint2 z; z.x = 0u; z.y = 0u;
      *(uint2*)(y_out + (size_t)NNODE * DDIM + voff) = z;
    }
    return;
  }
  int r0 = wv * 2, r1 = r0 + 1;
  int b0  = row_ptr[r0];              // uniform -> s_load
  int m01 = row_ptr[r0 + 1];
  int e1p = row_ptr[r0 + 2];
  // prefetch noise rows (consumed in epilogue, hidden under gathers)
  floatx4 n00 = __builtin_nontemporal_load((const floatx4*)(noise + (size_t)r0 * DDIM + l8 * 8));
  floatx4 n01 = __builtin_nontemporal_load((const floatx4*)(noise + (size_t)r0 * DDIM + l8 * 8 + 4));
  floatx4 n10 = __builtin_nontemporal_load((const floatx4*)(noise + (size_t)r1 * DDIM + l8 * 8));
  floatx4 n11 = __builtin_nontemporal_load((const floatx4*)(noise + (size_t)r1 * DDIM + l8 * 8 + 4));
  float scr0 = rsqrtf(fmaxf((float)counts[r0], 1.f));
  float scr1 = rsqrtf(fmaxf((float)counts[r1], 1.f));

  int c0 = min(m01 - b0, 64), c1 = min(e1p - m01, 64);
  int nit0 = (c0 + 7) >> 3, nit1 = (c1 + 7) >> 3;
  int d0 = __builtin_nontemporal_load(csr_dst + b0 + lane);    // csr padded by 64 ints
  int d1 = __builtin_nontemporal_load(csr_dst + m01 + lane);
  d0 = (lane < c0) ? d0 : NNODE;      // lanes past cnt -> dummy zero row
  d1 = (lane < c1) ? d1 : NNODE;

  floatx2 a00 = {0.f, 0.f}, a01 = {0.f, 0.f}, a02 = {0.f, 0.f}, a03 = {0.f, 0.f};
  floatx2 a10 = {0.f, 0.f}, a11 = {0.f, 0.f}, a12 = {0.f, 0.f}, a13 = {0.f, 0.f};
  {
    uint2 p0[8], p1[8];
    gather_issue(y_in, d0, nit0, g, voff, p0);   // all loads of both rows in flight
    gather_issue(y_in, d1, nit1, g, voff, p1);
    gather_acc(p0, nit0, a00, a01, a02, a03);
    gather_acc(p1, nit1, a10, a11, a12, a13);
  }
  for (int e0 = b0 + 64; e0 < m01; e0 += 64) {   // rare: deg > 64 tail, row0
    int cc = min(m01 - e0, 64);
    int nn = (cc + 7) >> 3;
    int dd = __builtin_nontemporal_load(csr_dst + e0 + lane);
    dd = (lane < cc) ? dd : NNODE;
    uint2 pp[8];
    gather_issue(y_in, dd, nn, g, voff, pp);
    gather_acc(pp, nn, a00, a01, a02, a03);
  }
  for (int e0 = m01 + 64; e0 < e1p; e0 += 64) {  // rare: deg > 64 tail, row1
    int cc = min(e1p - e0, 64);
    int nn = (cc + 7) >> 3;
    int dd = __builtin_nontemporal_load(csr_dst + e0 + lane);
    dd = (lane < cc) ? dd : NNODE;
    uint2 pp[8];
    gather_issue(y_in, dd, nn, g, voff, pp);
    gather_acc(pp, nn, a10, a11, a12, a13);
  }

  float acc0[8] = {a00[0], a00[1], a01[0], a01[1], a02[0], a02[1], a03[0], a03[1]};
  float acc1[8] = {a10[0], a10[1], a11[0], a11[1], a12[0], a12[1], a13[0], a13[1]};
#pragma unroll
  for (int m = 8; m <= 32; m <<= 1)
#pragma unroll
    for (int k = 0; k < 8; ++k) {
      acc0[k] += __shfl_xor(acc0[k], m, 64);
      acc1[k] += __shfl_xor(acc1[k], m, 64);
    }
  float nf0[8] = {n00[0], n00[1], n00[2], n00[3], n01[0], n01[1], n01[2], n01[3]};
  float nf1[8] = {n10[0], n10[1], n10[2], n10[3], n11[0], n11[1], n11[2], n11[3]};
  float ss0 = 0.f, ss1 = 0.f;
#pragma unroll
  for (int k = 0; k < 8; ++k) { ss0 += nf0[k] * nf0[k]; ss1 += nf1[k] * nf1[k]; }
#pragma unroll
  for (int m = 1; m <= 4; m <<= 1) {             // reduce across the 8 dim-slices
    ss0 += __shfl_xor(ss0, m, 64);
    ss1 += __shfl_xor(ss1, m, 64);
  }
  float inv0 = EPS_C / fmaxf(sqrtf(ss0), 1e-12f);
  float inv1 = EPS_C / fmaxf(sqrtf(ss1), 1e-12f);
  if (g == 0) {
    float ov[8];
#pragma unroll
    for (int k = 0; k < 8; ++k) {
      float x = acc0[k] * scr0 * YSI;
      float sgn = (x > 0.f) ? 1.f : ((x < 0.f) ? -1.f : 0.f);
      ov[k] = (x + sgn * nf0[k] * inv0) * scr0 * YS;
    }
    uint2 o;
    o.x = enc_pk4(ov[0], ov[1], ov[2], ov[3]);
    o.y = enc_pk4(ov[4], ov[5], ov[6], ov[7]);
    *(uint2*)(y_out + (size_t)r0 * DDIM + voff) = o;
  } else if (g == 1) {
    float ov[8];
#pragma unroll
    for (int k = 0; k < 8; ++k) {
      float x = acc1[k] * scr1 * YSI;
      float sgn = (x > 0.f) ? 1.f : ((x < 0.f) ? -1.f : 0.f);
      ov[k] = (x + sgn * nf1[k] * inv1) * scr1 * YS;
    }
    uint2 o;
    o.x = enc_pk4(ov[0], ov[1], ov[2], ov[3]);
    o.y = enc_pk4(ov[4], ov[5], ov[6], ov[7]);
    *(uint2*)(y_out + (size_t)r1 * DDIM + voff) = o;
  }
}

// ---------------- batch gather: BPR, reg, bf16 normalized InfoNCE inputs -------------
__global__ __launch_bounds__(256) void batch_kernel(
    const unsigned char* __restrict__ yb0, const unsigned char* __restrict__ yb1,
    const unsigned char* __restrict__ yb2,
    const float* __restrict__ ut, const float* __restrict__ it,
    const int* __restrict__ counts,
    const int* __restrict__ user, const int* __restrict__ pos, const int* __restrict__ neg,
    unsigned short* __restrict__ z1u, unsigned short* __restrict__ z2u,
    unsigned short* __restrict__ z1i, unsigned short* __restrict__ z2i,
    float* __restrict__ pos_u, float* __restrict__ pos_i,
    float* __restrict__ sp_arr, float* __restrict__ rr_arr) {
  int wave = blockIdx.x * (blockDim.x >> 6) + (threadIdx.x >> 6);
  int lane = threadIdx.x & 63;
  if (wave >= BB) return;
  int b = wave;
  int iu = user[b], ip = pos[b], ing = neg[b];
  float s_u = sqrtf(fmaxf((float)counts[iu], 1.f)) * YSI;
  float s_p = sqrtf(fmaxf((float)counts[UCNT + ip], 1.f)) * YSI;
  float s_n = sqrtf(fmaxf((float)counts[UCNT + ing], 1.f)) * YSI;
  size_t ru = (size_t)iu * DDIM + lane;
  size_t rp = (size_t)(UCNT + ip) * DDIM + lane;
  size_t rn = (size_t)(UCNT + ing) * DDIM + lane;
  float cu = fp8dec1(yb0[ru]) * s_u;        // x_cl user row
  float ci = fp8dec1(yb0[rp]) * s_p;        // x_cl positive-item row
  float ue = (cu + (fp8dec1(yb1[ru]) + fp8dec1(yb2[ru])) * s_u) * (1.f / 3.f);
  float pe = (ci + (fp8dec1(yb1[rp]) + fp8dec1(yb2[rp])) * s_p) * (1.f / 3.f);
  float ne = (fp8dec1(yb0[rn]) + fp8dec1(yb1[rn]) + fp8dec1(yb2[rn])) * s_n * (1.f / 3.f);

  float ps = wave_sum(ue * pe);
  float ns = wave_sum(ue * ne);
  float x = ns - ps;
  float sp = fmaxf(x, 0.f) + log1pf(expf(-fabsf(x)));

  float eu = ut[(size_t)iu * DDIM + lane];
  float ep = it[(size_t)ip * DDIM + lane];
  float en = it[(size_t)ing * DDIM + lane];
  float rr = wave_sum(eu * eu + ep * ep + en * en);
  if (lane == 0) { sp_arr[b] = sp; rr_arr[b] = rr; }

  float n1 = fmaxf(sqrtf(wave_sum(cu * cu)), 1e-12f);
  float n2 = fmaxf(sqrtf(wave_sum(ue * ue)), 1e-12f);
  float d12 = wave_sum(cu * ue);
  z1u[(size_t)b * DDIM + lane] = f2bf(cu / n1);
  z2u[(size_t)b * DDIM + lane] = f2bf(ue / n2);
  if (lane == 0) pos_u[b] = d12 / (n1 * n2) * INV_TEMP;

  float m1 = fmaxf(sqrtf(wave_sum(ci * ci)), 1e-12f);
  float m2 = fmaxf(sqrtf(wave_sum(pe * pe)), 1e-12f);
  float e12 = wave_sum(ci * pe);
  z1i[(size_t)b * DDIM + lane] = f2bf(ci / m1);
  z2i[(size_t)b * DDIM + lane] = f2bf(pe / m2);
  if (lane == 0) pos_i[b] = e12 / (m1 * m2) * INV_TEMP;
}

// ---------------- InfoNCE via MFMA: one wave = 16x16 tile, K=64 ----------------------
__global__ __launch_bounds__(256) void infonce_kernel(const unsigned short* __restrict__ Z1,
                                                      const unsigned short* __restrict__ Z2,
                                                      float* __restrict__ rowpart) {
  __shared__ float part[16];
  int t = threadIdx.x;
  if (t < 16) part[t] = 0.f;
  __syncthreads();
  int wv = t >> 6, lane = t & 63;
  int i0 = blockIdx.y * 16;              // 16-row i-tile (shared by 4 waves)
  int j0 = blockIdx.x * 64 + wv * 16;    // each wave: its own 16-col group
  int m = lane & 15, q = lane >> 4;
  const unsigned short* ap = Z1 + (size_t)(i0 + m) * DDIM + q * 8;
  const unsigned short* bp = Z2 + (size_t)(j0 + m) * DDIM + q * 8;
  shortx8 a0 = *(const shortx8*)ap;
  shortx8 a1 = *(const shortx8*)(ap + 32);
  shortx8 b0 = *(const shortx8*)bp;
  shortx8 b1 = *(const shortx8*)(bp + 32);
  floatx4 acc = {0.f, 0.f, 0.f, 0.f};
  acc = __builtin_amdgcn_mfma_f32_16x16x32_bf16(a0, b0, acc, 0, 0, 0);
  acc = __builtin_amdgcn_mfma_f32_16x16x32_bf16(a1, b1, acc, 0, 0, 0);
  float s[4];
#pragma unroll
  for (int r = 0; r < 4; ++r) s[r] = __expf(acc[r] * INV_TEMP);
#pragma unroll
  for (int mm = 1; mm <= 8; mm <<= 1)
#pragma unroll
    for (int r = 0; r < 4; ++r) s[r] += __shfl_xor(s[r], mm, 64);
  if (m == 0) {
#pragma unroll
    for (int r = 0; r < 4; ++r) atomicAdd(&part[q * 4 + r], s[r]);
  }
  __syncthreads();
  if (t < 16) rowpart[(size_t)blockIdx.x * BB + i0 + t] = part[t];
}

// ---------------- reduce 64 partials per row into rowsum ----------------
__global__ __launch_bounds__(256) void reduce_kernel(const float* __restrict__ rowpart_u,
                                                     const float* __restrict__ rowpart_i,
                                                     float* __restrict__ rowsum_u,
                                                     float* __restrict__ rowsum_i) {
  int i = blockIdx.x * 256 + threadIdx.x;   // row index
  const float* src = blockIdx.y ? rowpart_i : rowpart_u;
  float s = 0.f;
#pragma unroll 8
  for (int jb = 0; jb < NJT; ++jb) s += __builtin_nontemporal_load(src + (size_t)jb * BB + i);
  if (blockIdx.y) rowsum_i[i] = s; else rowsum_u[i] = s;
}

// ---------------- finalize ----------------
__global__ __launch_bounds__(256) void finalize_kernel(const float* __restrict__ rowsum_u,
                                                       const float* __restrict__ pos_u,
                                                       const float* __restrict__ rowsum_i,
                                                       const float* __restrict__ pos_i,
                                                       const float* __restrict__ sp_arr,
                                                       const float* __restrict__ rr_arr,
                                                       float* __restrict__ out) {
  int t = threadIdx.x;
  float su = 0.f, si = 0.f, sb = 0.f, sr = 0.f;
  for (int i = t; i < BB; i += 256) {
    su += logf(rowsum_u[i]) - pos_u[i];
    si += logf(rowsum_i[i]) - pos_i[i];
    sb += sp_arr[i];
    sr += rr_arr[i];
  }
  su = wave_sum(su);
  si = wave_sum(si);
  sb = wave_sum(sb);
  sr = wave_sum(sr);
  __shared__ float sh[16];
  int lane = t & 63, wid = t >> 6;
  if (lane == 0) { sh[wid] = su; sh[4 + wid] = si; sh[8 + wid] = sb; sh[12 + wid] = sr; }
  __syncthreads();
  if (t == 0) {
    float SU = sh[0] + sh[1] + sh[2] + sh[3];
    float SI = sh[4] + sh[5] + sh[6] + sh[7];
    float SB = sh[8] + sh[9] + sh[10] + sh[11];
    float SR = sh[12] + sh[13] + sh[14] + sh[15];
    out[0] = SB * (1.f / BB);
    out[1] = 1e-4f * 0.5f * SR * (1.f / BB);
    out[2] = 0.2f * ((SU + SI) * (1.f / BB));
  }
}

extern "C" void kernel_launch(void* const* d_in, const int* in_sizes, int n_in,
                              void* d_out, int out_size, void* d_ws, size_t ws_size,
                              hipStream_t stream) {
  const float* user_table = (const float*)d_in[0];
  const float* item_table = (const float*)d_in[1];
  const float* noise      = (const float*)d_in[3];
  const int*   edge_src   = (const int*)d_in[4];
  const int*   edge_dst   = (const int*)d_in[5];
  const int*   user       = (const int*)d_in[6];
  const int*   positive   = (const int*)d_in[7];
  const int*   negative   = (const int*)d_in[8];
  const int E2 = in_sizes[2];  // 2,000,000

  const int eh = E2 >> 1;
  const int nbu = (eh + EPB - 1) / EPB;            // 245
  const int nbi = (E2 - eh + EPB - 1) / EPB;       // 245
  const int nbp = nbu + nbi;                       // 490

  char* w = (char*)d_ws;
  auto alloc = [&](size_t bytes) -> void* {
    void* p = (void*)w;
    w += (bytes + 255) & ~(size_t)255;
    return p;
  };
  int*   cbase    = (int*)alloc((size_t)NRANGE * 4);
  int*   rtot     = (int*)alloc((size_t)NRANGE * 4);
  int*   bcnt     = (int*)alloc((size_t)NRANGE * nbp * 4);
  int*   boff     = (int*)alloc((size_t)NRANGE * nbp * 4);
  int*   row_ptr  = (int*)alloc((size_t)(NNODE + 1) * 4);
  int*   counts   = (int*)alloc((size_t)NNODE * 4);
  int*   csr_dst  = (int*)alloc((size_t)(E2 + 64) * 4);   // +64 pad: unpredicated chunk load
  unsigned* binned = (unsigned*)alloc((size_t)E2 * 4);
  unsigned char* y_init = (unsigned char*)alloc((size_t)(NNODE + 1) * DDIM);
  unsigned char* yb0    = (unsigned char*)alloc((size_t)(NNODE + 1) * DDIM);
  unsigned char* yb1    = (unsigned char*)alloc((size_t)(NNODE + 1) * DDIM);
  unsigned char* yb2    = (unsigned char*)alloc((size_t)(NNODE + 1) * DDIM);
  unsigned short* z1u    = (unsigned short*)alloc((size_t)BB * DDIM * 2);
  unsigned short* z2u    = (unsigned short*)alloc((size_t)BB * DDIM * 2);
  unsigned short* z1i    = (unsigned short*)alloc((size_t)BB * DDIM * 2);
  unsigned short* z2i    = (unsigned short*)alloc((size_t)BB * DDIM * 2);
  float* pos_u    = (float*)alloc((size_t)BB * 4);
  float* pos_i    = (float*)alloc((size_t)BB * 4);
  float* rowsum_u = (float*)alloc((size_t)BB * 4);
  float* rowsum_i = (float*)alloc((size_t)BB * 4);
  float* sp_arr   = (float*)alloc((size_t)BB * 4);
  float* rr_arr   = (float*)alloc((size_t)BB * 4);
  float* rowpart_u = (float*)alloc((size_t)NJT * BB * 4);
  float* rowpart_i = (float*)alloc((size_t)NJT * BB * 4);

  pcount_kernel<<<nbp, 256, 0, stream>>>(edge_src, bcnt, E2, nbu, nbp);
  pscan_kernel<<<NRANGE, 256, 0, stream>>>(bcnt, boff, rtot, nbp);
  cscan2_kernel<<<1, 512, 0, stream>>>(rtot, cbase, row_ptr, E2);
  pscatter_kernel<<<nbp, 256, 0, stream>>>(edge_src, edge_dst, boff, cbase, binned,
                                           E2, nbu, nbp);
  place_kernel<<<NRANGE, 256, 0, stream>>>(binned, cbase, row_ptr, counts, csr_dst, E2);
  prescale_kernel<<<((NNODE + 1) * 16 + 255) / 256, 256, 0, stream>>>(user_table, item_table,
                                                                      counts, y_init);
  const int spmm_waves = NNODE / 2 + 1;         // 2 rows per wave + dummy-row wave
  const int spmm_blocks = (spmm_waves + 3) / 4; // 4 waves per 256-thread block
  spmm_kernel<<<spmm_blocks, 256, 0, stream>>>(y_init, row_ptr, csr_dst, counts,
                                               noise + (size_t)0 * NNODE * DDIM, yb0);
  spmm_kernel<<<spmm_blocks, 256, 0, stream>>>(yb0, row_ptr, csr_dst, counts,
                                               noise + (size_t)1 * NNODE * DDIM, yb1);
  spmm_kernel<<<spmm_blocks, 256, 0, stream>>>(yb1, row_ptr, csr_dst, counts,
                                               noise + (size_t)2 * NNODE * DDIM, yb2);
  batch_kernel<<<BB / 4, 256, 0, stream>>>(yb0, yb1, yb2, user_table, item_table, counts,
                                           user, positive, negative,
                                           z1u, z2u, z1i, z2i, pos_u, pos_i, sp_arr, rr_arr);
  dim3 ig(NJT, BB / 16);
  infonce_kernel<<<ig, 256, 0, stream>>>(z1u, z2u, rowpart_u);
  infonce_kernel<<<ig, 256, 0, stream>>>(z1i, z2i, rowpart_i);
  dim3 rg(BB / 256, 2);
  reduce_kernel<<<rg, 256, 0, stream>>>(rowpart_u, rowpart_i, rowsum_u, rowsum_i);
  finalize_kernel<<<1, 256, 0, stream>>>(rowsum_u, pos_u, rowsum_i, pos_i,
                                         sp_arr, rr_arr, (float*)d_out);
}